// Round 9
// baseline (386.340 us; speedup 1.0000x reference)
//
#include <hip/hip_runtime.h>

// FourierFilter: per-(b,c) rfft-4096 -> top-k (80% energy) spectral mask -> irfft.
// x:[32,4096,128] f32. out = concat(x_var, x_inv), each [32,4096,128].
// SINGLE fused kernel: one 512-thread block handles 2 ADJACENT channels of one batch
// (2 independent 256-thread FFT "groups"). 34KB LDS -> 4 blocks/CU (32 waves = cap):
// 4 independent phase-offset blocks per CU overlap memory phases with compute phases,
// and barriers sync 8 waves instead of 16 (round-9 change; r8's 1024-thr/68KB shape
// had 2 lockstep blocks/CU and near-zero phase overlap).
// Global traffic float2 (8B/lane), CACHED (r5 lesson: nt breaks L2 write-combining of
// the 8 sibling blocks' partial-line stores -> RMW). Selection: 31-iter bit bisection
// (r6 lesson: radix-select LDS-atomic hot bins cost 40us). Twiddles: __sincosf chains
// (HW transcendental; r7 lesson: tables spill + add latency). Store-phase x re-loads
// hoisted above LDS reads (r8; live range store-phase-only — r3 lesson: holding x
// across FFTs spills).
// XCD swizzle: the 8 blocks sharing each 64B x/out line are m-consecutive on one XCD.

#define TLEN 4096
#define N2   2048
#define CCH  128
#define BB   32
#define HALF 16777216  // 32*4096*128
#define PI_F 3.14159265358979323846f

// LDS pad swizzle for FFT arrays
#define LP(i) ((i) + ((i) >> 5))
#define ZLEN 2113      // LP(2048) + safety

__device__ __forceinline__ void cmul(float& r, float& i, float br, float bi) {
  float tr = r * br - i * bi;
  i = r * bi + i * br;
  r = tr;
}

__device__ __forceinline__ void dft4(float vr[4], float vi[4], float s) {
  float t0r = vr[0] + vr[2], t0i = vi[0] + vi[2];
  float t1r = vr[0] - vr[2], t1i = vi[0] - vi[2];
  float t2r = vr[1] + vr[3], t2i = vi[1] + vi[3];
  float d3r = vr[1] - vr[3], d3i = vi[1] - vi[3];
  float t3r = -s * d3i, t3i = s * d3r;
  vr[0] = t0r + t2r; vi[0] = t0i + t2i;
  vr[1] = t1r + t3r; vi[1] = t1i + t3i;
  vr[2] = t0r - t2r; vi[2] = t0i - t2i;
  vr[3] = t1r - t3r; vi[3] = t1i - t3i;
}

__device__ __forceinline__ void dft8(float vr[8], float vi[8], float s) {
  float er[4]  = {vr[0], vr[2], vr[4], vr[6]};
  float ei[4]  = {vi[0], vi[2], vi[4], vi[6]};
  float odr[4] = {vr[1], vr[3], vr[5], vr[7]};
  float odi[4] = {vi[1], vi[3], vi[5], vi[7]};
  dft4(er, ei, s);
  dft4(odr, odi, s);
  const float c = 0.70710678118654752440f;
  float wr[4] = {1.0f, c, 0.0f, -c};
  float wi[4] = {0.0f, s * c, s, s * c};
  #pragma unroll
  for (int k = 0; k < 4; ++k) {
    float tr = wr[k] * odr[k] - wi[k] * odi[k];
    float ti = wr[k] * odi[k] + wi[k] * odr[k];
    vr[k]     = er[k] + tr; vi[k]     = ei[k] + ti;
    vr[k + 4] = er[k] - tr; vi[k + 4] = ei[k] - ti;
  }
}

__device__ __forceinline__ void stage8_first(float* zr, float* zi, int tid, float s) {
  float vr[8], vi[8];
  #pragma unroll
  for (int r = 0; r < 8; ++r) {
    int idx = LP(tid + (r << 8));
    vr[r] = zr[idx]; vi[r] = zi[idx];
  }
  dft8(vr, vi, s);
  __syncthreads();
  #pragma unroll
  for (int r = 0; r < 8; ++r) {
    int idx = LP((tid << 3) + r);
    zr[idx] = vr[r]; zi[idx] = vi[r];
  }
  __syncthreads();
}

template <int NS>
__device__ __forceinline__ void stage8_tw(float* zr, float* zi, int tid, float s) {
  int j = tid;
  int p = j & (NS - 1);
  float vr[8], vi[8];
  #pragma unroll
  for (int r = 0; r < 8; ++r) {
    int idx = LP(j + (r << 8));
    vr[r] = zr[idx]; vi[r] = zi[idx];
  }
  float ang = s * 6.28318530717958647692f * (float)p / (float)(NS * 8);
  float s1, c1; __sincosf(ang, &s1, &c1);
  float c2 = c1 * c1 - s1 * s1, s2 = 2.0f * c1 * s1;
  float c3 = c2 * c1 - s2 * s1, s3 = c2 * s1 + s2 * c1;
  float c4 = c2 * c2 - s2 * s2, s4 = 2.0f * c2 * s2;
  float c5 = c4 * c1 - s4 * s1, s5 = c4 * s1 + s4 * c1;
  float c6 = c4 * c2 - s4 * s2, s6 = c4 * s2 + s4 * c2;
  float c7 = c4 * c3 - s4 * s3, s7 = c4 * s3 + s4 * c3;
  cmul(vr[1], vi[1], c1, s1);
  cmul(vr[2], vi[2], c2, s2);
  cmul(vr[3], vi[3], c3, s3);
  cmul(vr[4], vi[4], c4, s4);
  cmul(vr[5], vi[5], c5, s5);
  cmul(vr[6], vi[6], c6, s6);
  cmul(vr[7], vi[7], c7, s7);
  dft8(vr, vi, s);
  __syncthreads();
  int idxD = ((j - p) << 3) + p;
  #pragma unroll
  for (int r = 0; r < 8; ++r) {
    int idx = LP(idxD + r * NS);
    zr[idx] = vr[r]; zi[idx] = vi[r];
  }
  __syncthreads();
}

__device__ __forceinline__ void stage4_last(float* zr, float* zi, int tid, float s) {
  #pragma unroll
  for (int half = 0; half < 2; ++half) {
    int j = tid + (half << 8);
    float ang = s * PI_F * (float)j * (1.0f / 1024.0f);
    float s1, c1; __sincosf(ang, &s1, &c1);
    float c2 = c1 * c1 - s1 * s1, s2 = 2.0f * c1 * s1;
    float c3 = c2 * c1 - s2 * s1, s3 = c2 * s1 + s2 * c1;
    float vr[4], vi[4];
    #pragma unroll
    for (int r = 0; r < 4; ++r) {
      int idx = LP(j + (r << 9));
      vr[r] = zr[idx]; vi[r] = zi[idx];
    }
    cmul(vr[1], vi[1], c1, s1);
    cmul(vr[2], vi[2], c2, s2);
    cmul(vr[3], vi[3], c3, s3);
    dft4(vr, vi, s);
    #pragma unroll
    for (int r = 0; r < 4; ++r) {
      int idx = LP(j + (r << 9));
      zr[idx] = vr[r]; zi[idx] = vi[r];
    }
  }
  __syncthreads();
}

__device__ __forceinline__ void fft2048(float* zr, float* zi, int tid, float s) {
  stage8_first(zr, zi, tid, s);
  stage8_tw<8>(zr, zi, tid, s);
  stage8_tw<64>(zr, zi, tid, s);
  stage4_last(zr, zi, tid, s);
}

// Group-level (256-thread) reduction inside a 512-thread block; all threads call it.
__device__ __forceinline__ float group_sum(float v, float* redg, int tg, int bank) {
  #pragma unroll
  for (int o = 32; o > 0; o >>= 1) v += __shfl_down(v, o, 64);
  if ((tg & 63) == 0) redg[(bank << 2) + (tg >> 6)] = v;
  __syncthreads();
  int b4 = bank << 2;
  return redg[b4] + redg[b4 + 1] + redg[b4 + 2] + redg[b4 + 3];
}

// One 512-thread block per (batch b, channel-pair cg2): 2 independent FFT groups.
__global__ __launch_bounds__(512, 8) void fourier_filter_fused(const float* __restrict__ x,
                                                               float* __restrict__ xvar,
                                                               float* __restrict__ xinv) {
  // z[0]=real planes, z[1]=imag planes; plane g = series for channel cbase+g.
  __shared__ float z[2][2][ZLEN];
  __shared__ float red[16];   // 8 floats per group (2 banks x 4 waves), 2 groups

  int tidx = threadIdx.x;

  // XCD swizzle: bid = m*8 + r round-robins r across XCDs. Decompose m so the 8
  // blocks sharing each 64B line (same b, same 16-channel line-group, ol=0..7) are
  // m-consecutive on the same XCD r; the line-group rotates with (r+b) for balance.
  int bid = blockIdx.x;
  int r = bid & 7;            // XCD under round-robin dispatch
  int m = bid >> 3;           // 0..255
  int b = m >> 3;             // 0..31
  int ol = m & 7;             // pair-within-line-group
  int cg2 = (((r + b) & 7) << 3) | ol;  // channel-pair 0..63
  int cbase = cg2 << 1;

  const float* xp = x + (size_t)b * (TLEN * CCH) + cbase;

  // ---- Load: thread covers time t; float2 spans the block's 2 channels. ----
  // (Do NOT hold x in registers across the FFTs: spills — round-3 lesson.)
  #pragma unroll
  for (int it = 0; it < 8; ++it) {
    int t = tidx + (it << 9);
    float2 v = *(const float2*)(xp + (size_t)t * CCH);
    float* dst = &z[t & 1][0][0];       // parity -> real/imag plane (no branch)
    int k = LP(t >> 1);
    dst[k]        = v.x;
    dst[ZLEN + k] = v.y;
  }
  __syncthreads();

  int g  = tidx >> 8;         // FFT group = channel within pair
  int tg = tidx & 255;        // thread-in-group
  float* Zr = z[0][g];
  float* Zi = z[1][g];
  float* redg = red + (g << 3);

  fft2048(Zr, Zi, tg, -1.0f);   // forward

  // ---- Unpack to rfft bins X[0..2048] IN PLACE; energies in regs. ----
  float eb[9];
  eb[8] = 0.0f;
  const float RC  = 0.92387953251128675613f;   // cos(pi/8)
  const float RSn = -0.38268343236508977173f;  // -sin(pi/8)
  float ws, wc;
  __sincosf(-PI_F * (float)tg * (1.0f / 2048.0f), &ws, &wc);
  #pragma unroll
  for (int jj = 0; jj < 4; ++jj) {
    int k = tg + (jj << 8);
    int mkz = (N2 - k) & (N2 - 1);
    int ik = LP(k), im = LP(N2 - k);
    float akr = Zr[ik],      aki = Zi[ik];
    float bkr = Zr[LP(mkz)], bki = Zi[LP(mkz)];
    float Er  = 0.5f * (akr + bkr);
    float Ei  = 0.5f * (aki - bki);
    float Or_ = 0.5f * (aki + bki);
    float Oi  = 0.5f * (bkr - akr);
    float tr = wc * Or_ - ws * Oi;
    float ti = wc * Oi + ws * Or_;
    float x0r = Er + tr, x0i = Ei + ti;
    float x1r = Er - tr, x1i = ti - Ei;
    Zr[ik] = x0r; Zi[ik] = x0i;
    Zr[im] = x1r; Zi[im] = x1i;
    eb[2 * jj]     = x0r * x0r + x0i * x0i;
    eb[2 * jj + 1] = x1r * x1r + x1i * x1i;
    float nwc = wc * RC - ws * RSn;
    ws = wc * RSn + ws * RC; wc = nwc;
  }
  if (tg == 0) {
    int i4 = LP(1024);
    float re = Zr[i4], im_ = Zi[i4];
    Zi[i4] = -im_;
    eb[8] = re * re + im_ * im_;
  }

  // ---- Selection: tau = max tau s.t. sum(e >= tau) > 0.8*total (per group). ----
  float tloc = 0.0f;
  #pragma unroll
  for (int s = 0; s < 9; ++s) tloc += eb[s];
  float total = group_sum(tloc, redg, tg, 0);
  float thresh = 0.8f * total;

  unsigned lo = 0u, hi = 0x7F7FFFFFu;
  for (int it = 0; it < 31; ++it) {
    unsigned mid = (lo + hi + 1u) >> 1;
    float tau = __uint_as_float(mid);
    float loc = 0.0f;
    #pragma unroll
    for (int s = 0; s < 9; ++s) loc += (eb[s] >= tau) ? eb[s] : 0.0f;
    float ssum = group_sum(loc, redg, tg, (it + 1) & 1);
    if (ssum > thresh) lo = mid; else hi = mid - 1;
  }
  float tau = __uint_as_float(lo);

  // ---- Mask + hermitian repack IN PLACE. ----
  const float RSp = 0.38268343236508977173f;
  __sincosf(PI_F * (float)tg * (1.0f / 2048.0f), &ws, &wc);
  #pragma unroll
  for (int jj = 0; jj < 4; ++jj) {
    int k = tg + (jj << 8);
    int ik = LP(k), im = LP(N2 - k);
    float xkr = Zr[ik], xki = Zi[ik];
    float xmr = Zr[im], xmi = Zi[im];
    float ekk = xkr * xkr + xki * xki;
    float emm = xmr * xmr + xmi * xmi;
    if (ekk >= tau) { xkr = 0.0f; xki = 0.0f; }
    if (emm >= tau) { xmr = 0.0f; xmi = 0.0f; }
    float Er = 0.5f * (xkr + xmr);
    float Ei = 0.5f * (xki - xmi);
    float Br = 0.5f * (xkr - xmr);
    float Bi = 0.5f * (xki + xmi);
    float Or_ = wc * Br - ws * Bi;
    float Oi  = wc * Bi + ws * Br;
    Zr[ik] = Er - Oi;  Zi[ik] = Ei + Or_;
    Zr[im] = Er + Oi;  Zi[im] = Or_ - Ei;
    float nwc = wc * RC - ws * RSp;
    ws = wc * RSp + ws * RC; wc = nwc;
  }
  if (tg == 0) {
    int i4 = LP(1024);
    float re = Zr[i4], im_ = Zi[i4];
    float e = re * re + im_ * im_;
    if (e >= tau) { re = 0.0f; im_ = 0.0f; }
    Zr[i4] = re; Zi[i4] = -im_;
  }
  __syncthreads();

  fft2048(Zr, Zi, tg, 1.0f);    // inverse (unscaled); ends with __syncthreads()

  // ---- Store: xvar float2 across the 2 channels; xinv = x - xvar. ----
  // CACHED loads/stores (r5 lesson: nt breaks L2 write-combining -> RMW).
  // x re-loads hoisted above the LDS reads (r8); live range is store-phase-only.
  const float scale = 1.0f / 2048.0f;
  size_t base = (size_t)b * (TLEN * CCH) + cbase;
  float2 xv[8];
  #pragma unroll
  for (int it = 0; it < 8; ++it) {
    int t = tidx + (it << 9);
    xv[it] = *(const float2*)(x + base + (size_t)t * CCH);
  }
  #pragma unroll
  for (int it = 0; it < 8; ++it) {
    int t = tidx + (it << 9);
    const float* src = &z[t & 1][0][0];
    int k = LP(t >> 1);
    float2 v;
    v.x = src[k]        * scale;
    v.y = src[ZLEN + k] * scale;
    size_t off = base + (size_t)t * CCH;
    *(float2*)(xvar + off) = v;
    *(float2*)(xinv + off) = make_float2(xv[it].x - v.x, xv[it].y - v.y);
  }
}

extern "C" void kernel_launch(void* const* d_in, const int* in_sizes, int n_in,
                              void* d_out, int out_size, void* d_ws, size_t ws_size,
                              hipStream_t stream) {
  const float* x = (const float*)d_in[0];
  float* out  = (float*)d_out;
  float* xvar = out;
  float* xinv = out + HALF;

  (void)d_ws; (void)ws_size;
  fourier_filter_fused<<<BB * 64, 512, 0, stream>>>(x, xvar, xinv);
}